// Round 6
// baseline (722.398 us; speedup 1.0000x reference)
//
#include <hip/hip_runtime.h>
#include <hip/hip_cooperative_groups.h>

namespace cg = cooperative_groups;

// GCNEncoder — round 16: fuse the whole CSR build into ONE cooperative kernel.
// R15 counters: k_agg1 (100us) is near its L2-miss-path floor; the slack is
// the serial build chain (2 memsets + prepw + hist + scan + scatter + fine =
// 7 dispatches, incl. a 25.6MB edge-list RE-READ and a 1-block scan).
// k_build (hipLaunchCooperativeKernel, 391 blocks):
//   phase0: init gcnt/spart, prepw (blocks 0-11), bin 16 edges/thread into
//           LDS lcnt; edge data kept in REGISTERS across grid.sync()
//   phase1: lcnt -> global gcnt atomics
//   phase2: block 0 scans bucket totals -> gbase/gcur (others wait)
//   phase3: per-block run reservation + scatter from registers (no re-read)
//   phase4: per-bucket CSR finalize (reuses same LDS)
// Edge list read ONCE. Launches 12 -> 6. Everything else unchanged from R15.

#define SHIFT 8
#define BSZ   256          // nodes per bucket = 1<<SHIFT
#define CHUNK 4096         // edges per block in build
#define EPT   (CHUNK/256)  // edges per thread = 16
#define NBMAX 1024         // supports N <= 262144

typedef short bf16x8 __attribute__((ext_vector_type(8)));
typedef float f32x4  __attribute__((ext_vector_type(4)));

__device__ __forceinline__ unsigned short f2bf(float f) {
    unsigned int u = __float_as_uint(f);
    unsigned int r = (u + 0x7FFFu + ((u >> 16) & 1u)) >> 16;   // RNE
    return (unsigned short)r;
}
__device__ __forceinline__ float bf2f(unsigned short h) {
    return __uint_as_float(((unsigned int)h) << 16);
}
// exact hi/lo split of a float pair, packed as bf16x2 (truncation split:
// x == bf2f(hi) + lo exactly; lo then truncated to bf16, residual ~2^-17|x|)
__device__ __forceinline__ void split2(float a, float b, unsigned int& hi, unsigned int& lo) {
    unsigned int ua = __float_as_uint(a), ub = __float_as_uint(b);
    unsigned int ha = ua & 0xFFFF0000u,  hb = ub & 0xFFFF0000u;
    hi = (ha >> 16) | hb;
    float la = a - __uint_as_float(ha);
    float lb = b - __uint_as_float(hb);
    lo = (__float_as_uint(la) >> 16) | (__float_as_uint(lb) & 0xFFFF0000u);
}
// dtype probe, computed per-block (reads 16 L2-hot ints): 1 => int64 input
__device__ __forceinline__ int detect64(const int* __restrict__ p) {
    int o = 0;
#pragma unroll
    for (int q = 0; q < 16; ++q) o |= p[2 * q + 1];
    return (o == 0) ? 1 : 0;
}

// ---------- cooperative build: hist+scan+scatter+fine+prepw+inits ----------
__global__ __launch_bounds__(256) void k_build(const void* __restrict__ eiv,
                                               int E, int N, int NB,
                                               int* __restrict__ gcnt,
                                               int* __restrict__ gbase,
                                               int* __restrict__ gcur,
                                               unsigned int* __restrict__ ebuf,
                                               int* __restrict__ cnt,
                                               float* __restrict__ dis,
                                               int* __restrict__ rowptr,
                                               int* __restrict__ elist,
                                               const float* __restrict__ W1,
                                               const float* __restrict__ W2,
                                               uint4* __restrict__ Whi1,
                                               uint4* __restrict__ Wlo1,
                                               uint4* __restrict__ Whi2,
                                               uint4* __restrict__ Wlo2,
                                               float* __restrict__ spart) {
    cg::grid_group grid = cg::this_grid();
    __shared__ int lcnt[NBMAX];
    __shared__ int lbase[NBMAX];
    __shared__ int ssum[256];
    int t = threadIdx.x, b = blockIdx.x;
    int stride = gridDim.x * 256;
    int gid = b * 256 + t;

    // ---- phase 0: global inits + prepw + local binning ----
    for (int u = gid; u < 1024; u += stride) gcnt[u] = 0;
    for (int u = gid; u < 16384; u += stride) spart[u] = 0.f;
    if (b < 12) {   // W1+W2 fragment conversion (3072 slots)
        int idx = gid;
        const float* W = 0; uint4 *H = 0, *L = 0; int slot = -1;
        if (idx < 2048)      { W = W1; H = Whi1; L = Wlo1; slot = idx; }
        else if (idx < 3072) { W = W2; H = Whi2; L = Wlo2; slot = idx - 2048; }
        if (slot >= 0) {
            int lane = slot & 63, kt = (slot >> 6) & 3, nt = slot >> 8;
            int o = nt * 16 + (lane & 15);
            int k0 = kt * 32 + (lane >> 4) * 8;
            const float* p = W + (size_t)o * 128 + k0;
            unsigned int h[4], l[4];
#pragma unroll
            for (int pr = 0; pr < 4; ++pr) split2(p[2 * pr], p[2 * pr + 1], h[pr], l[pr]);
            H[slot] = make_uint4(h[0], h[1], h[2], h[3]);
            L[slot] = make_uint4(l[0], l[1], l[2], l[3]);
        }
    }
    for (int u = t; u < NB; u += 256) lcnt[u] = 0;
    __syncthreads();
    int base = b * CHUNK;
    int f = detect64((const int*)eiv);
    const long long* e64 = (const long long*)eiv;
    const int*       e32 = (const int*)eiv;
    unsigned int ent[EPT];
    int bk[EPT];
    int off[EPT];
#pragma unroll
    for (int r = 0; r < EPT; ++r) {
        int e = base + r * 256 + t;
        bk[r] = -1;
        if (e < E) {
            int s, d;
            if (f) { s = (int)e64[e]; d = (int)e64[E + e]; }
            else   { s = e32[e];      d = e32[E + e]; }
            if ((unsigned)s < (unsigned)N && (unsigned)d < (unsigned)N) {
                int bb = d >> SHIFT;
                bk[r]  = bb;
                off[r] = atomicAdd(&lcnt[bb], 1);
                ent[r] = ((unsigned int)(d & (BSZ - 1)) << 24) | (unsigned int)s;
            }
        }
    }
    __threadfence();
    grid.sync();

    // ---- phase 1: local hist -> global ----
    for (int u = t; u < NB; u += 256) {
        int c = lcnt[u];
        if (c) atomicAdd(&gcnt[u], c);
    }
    __threadfence();
    grid.sync();

    // ---- phase 2: block 0 scans bucket totals (1024 = 256 thr x 4) ----
    if (b == 0) {
        int v0 = gcnt[4 * t], v1 = gcnt[4 * t + 1], v2 = gcnt[4 * t + 2], v3 = gcnt[4 * t + 3];
        int tsum = v0 + v1 + v2 + v3;
        ssum[t] = tsum;
        __syncthreads();
        for (int o = 1; o < 256; o <<= 1) {
            int x = ssum[t];
            int y = (t >= o) ? ssum[t - o] : 0;
            __syncthreads();
            ssum[t] = x + y;
            __syncthreads();
        }
        int ex = ssum[t] - tsum;
        int e0 = ex, e1 = ex + v0, e2 = e1 + v1, e3 = e2 + v2;
        gbase[4 * t] = e0;  gcur[4 * t] = e0;
        gbase[4 * t + 1] = e1; gcur[4 * t + 1] = e1;
        gbase[4 * t + 2] = e2; gcur[4 * t + 2] = e2;
        gbase[4 * t + 3] = e3; gcur[4 * t + 3] = e3;
        if (t == 255) gbase[NB] = ssum[255];
    }
    __threadfence();
    grid.sync();

    // ---- phase 3: run reservation + scatter from registers ----
    for (int u = t; u < NB; u += 256) {
        int c = lcnt[u];
        lbase[u] = c ? atomicAdd(&gcur[u], c) : 0;
    }
    __syncthreads();
#pragma unroll
    for (int r = 0; r < EPT; ++r)
        if (bk[r] >= 0) ebuf[(size_t)lbase[bk[r]] + off[r]] = ent[r];
    __threadfence();
    grid.sync();

    // ---- phase 4: per-bucket CSR finalize (reuse lcnt/lbase as lc/ls) ----
    if (b < NB) {
        int start = gbase[b], end = gbase[b + 1];
        int m = end - start;
        lcnt[t] = 0;
        __syncthreads();
        for (int j = t; j < m; j += 256)
            atomicAdd(&lcnt[ebuf[start + j] >> 24], 1);
        __syncthreads();
        int v = lcnt[t];
        lbase[t] = v;
        __syncthreads();
        for (int o = 1; o < BSZ; o <<= 1) {
            int x = lbase[t];
            int y = (t >= o) ? lbase[t - o] : 0;
            __syncthreads();
            lbase[t] = x + y;
            __syncthreads();
        }
        int ex = lbase[t] - v;
        int i = (b << SHIFT) + t;
        if (i < N) {
            cnt[i]    = v;
            dis[i]    = rsqrtf((float)v + 1.0f);
            rowptr[i] = start + ex;
        }
        lcnt[t] = ex;        // per-node cursor (bucket-relative)
        __syncthreads();
        for (int j = t; j < m; j += 256) {
            unsigned int e = ebuf[start + j];
            int p = atomicAdd(&lcnt[e >> 24], 1);
            elist[start + p] = (int)(e & 0xFFFFFFu);
        }
    }
}

// ---------- GEMM1 (MFMA): h1s[n][o] (bf16) = dis[n] * (x[n]·W1[o]) ----------
__global__ __launch_bounds__(256) void k_gemm1(const float* __restrict__ x,
                                               const uint4* __restrict__ Whi,
                                               const uint4* __restrict__ Wlo,
                                               const float* __restrict__ dis,
                                               unsigned short* __restrict__ h1b, int N) {
    __shared__ uint4 Ahi[1024];   // [ (c*4+kt)*64 + lane ]
    __shared__ uint4 Alo[1024];
    int t = threadIdx.x;
    int n0 = blockIdx.x * 64;
    // ---- phase 1: x -> hi/lo fragments in LDS ----
    for (int s = t; s < 1024; s += 256) {
        int lane = s & 63, kt = (s >> 6) & 3, c = s >> 8;
        int row = n0 + c * 16 + (lane & 15);
        int rr = min(row, N - 1);
        int k0 = kt * 32 + (lane >> 4) * 8;
        const float4* p = (const float4*)(x + (size_t)rr * 128 + k0);
        float4 u0 = p[0], u1 = p[1];
        unsigned int h0, h1, h2, h3, l0, l1, l2, l3;
        split2(u0.x, u0.y, h0, l0);
        split2(u0.z, u0.w, h1, l1);
        split2(u1.x, u1.y, h2, l2);
        split2(u1.z, u1.w, h3, l3);
        Ahi[s] = make_uint4(h0, h1, h2, h3);
        Alo[s] = make_uint4(l0, l1, l2, l3);
    }
    __syncthreads();
    // ---- phase 2: MFMA ----
    int w = t >> 6, lane = t & 63;
    bf16x8 ah[4], al[4];
#pragma unroll
    for (int kt = 0; kt < 4; ++kt) {
        ah[kt] = ((const bf16x8*)Ahi)[(w * 4 + kt) * 64 + lane];
        al[kt] = ((const bf16x8*)Alo)[(w * 4 + kt) * 64 + lane];
    }
    f32x4 acc[8];
#pragma unroll
    for (int nt = 0; nt < 8; ++nt) {
        acc[nt] = (f32x4)(0.f);
#pragma unroll
        for (int kt = 0; kt < 4; ++kt) {
            bf16x8 bh = ((const bf16x8*)Whi)[(nt * 4 + kt) * 64 + lane];
            bf16x8 bl = ((const bf16x8*)Wlo)[(nt * 4 + kt) * 64 + lane];
            acc[nt] = __builtin_amdgcn_mfma_f32_16x16x32_bf16(ah[kt], bh, acc[nt], 0, 0, 0);
            acc[nt] = __builtin_amdgcn_mfma_f32_16x16x32_bf16(ah[kt], bl, acc[nt], 0, 0, 0);
            acc[nt] = __builtin_amdgcn_mfma_f32_16x16x32_bf16(al[kt], bh, acc[nt], 0, 0, 0);
        }
    }
    // ---- epilogue: scale by dis, pack bf16, store ----
    int r0 = n0 + w * 16 + (lane >> 4) * 4;
    float dv[4];
#pragma unroll
    for (int r = 0; r < 4; ++r) {
        int row = r0 + r;
        dv[r] = (row < N) ? dis[row] : 0.f;
    }
#pragma unroll
    for (int nt = 0; nt < 8; ++nt) {
        int col = nt * 16 + (lane & 15);
#pragma unroll
        for (int r = 0; r < 4; ++r) {
            int row = r0 + r;
            if (row < N) h1b[(size_t)row * 128 + col] = f2bf(dv[r] * acc[nt][r]);
        }
    }
}

// ---------- layer-1 gather + fused BN-stats, 16 nodes/block ----------
__global__ __launch_bounds__(256) void k_agg1(const unsigned int* __restrict__ h1b,
                                              const float* __restrict__ dis,
                                              const int* __restrict__ rowptr,
                                              const int* __restrict__ cnt,
                                              const int* __restrict__ elist,
                                              float* __restrict__ agg1,
                                              float* __restrict__ spart, int N) {
    int t = threadIdx.x;
    int lane = t & 63;
    int i0 = blockIdx.x * 16 + (t >> 6) * 4;
    float sx = 0.f, sy = 0.f, qx = 0.f, qy = 0.f;
#pragma unroll
    for (int k = 0; k < 4; ++k) {
        int i = i0 + k;
        bool act = (i < N);
        float accx = 0.f, accy = 0.f;
        int base = 0, c = 0;
        if (act) { base = rowptr[i]; c = cnt[i]; }
        int j = 0;
        for (; j + 16 <= c; j += 16) {
            int ss[16];
#pragma unroll
            for (int r = 0; r < 16; ++r) ss[r] = elist[base + j + r];
            unsigned int vv[16];
#pragma unroll
            for (int r = 0; r < 16; ++r) vv[r] = h1b[(size_t)ss[r] * 64 + lane];  // 256B/row
#pragma unroll
            for (int r = 0; r < 16; ++r) {
                accx += bf2f((unsigned short)(vv[r] & 0xFFFF));
                accy += bf2f((unsigned short)(vv[r] >> 16));
            }
        }
        if (j + 8 <= c) {
            int ss[8];
#pragma unroll
            for (int r = 0; r < 8; ++r) ss[r] = elist[base + j + r];
            unsigned int vv[8];
#pragma unroll
            for (int r = 0; r < 8; ++r) vv[r] = h1b[(size_t)ss[r] * 64 + lane];
#pragma unroll
            for (int r = 0; r < 8; ++r) {
                accx += bf2f((unsigned short)(vv[r] & 0xFFFF));
                accy += bf2f((unsigned short)(vv[r] >> 16));
            }
            j += 8;
        }
        for (; j < c; ++j) {
            int s = elist[base + j];
            unsigned int v = h1b[(size_t)s * 64 + lane];
            accx += bf2f((unsigned short)(v & 0xFFFF));
            accy += bf2f((unsigned short)(v >> 16));
        }
        if (act) {
            float di = dis[i];
            unsigned int sv = h1b[(size_t)i * 64 + lane];
            float rx = di * (accx + bf2f((unsigned short)(sv & 0xFFFF)));
            float ry = di * (accy + bf2f((unsigned short)(sv >> 16)));
            ((float2*)agg1)[(size_t)i * 64 + lane] = make_float2(rx, ry);
            sx += rx; sy += ry; qx += rx * rx; qy += ry * ry;
        }
    }
    // ---- fused BN partial stats: features 2*lane, 2*lane+1 ----
    __shared__ float4 red[256];
    red[t] = make_float4(sx, sy, qx, qy);
    __syncthreads();
    if (t < 64) {
        float4 a = red[t], b = red[t + 64], cc = red[t + 128], d = red[t + 192];
        float ssx = a.x + b.x + cc.x + d.x;
        float ssy = a.y + b.y + cc.y + d.y;
        float sqx = a.z + b.z + cc.z + d.z;
        float sqy = a.w + b.w + cc.w + d.w;
        float* sp = spart + ((size_t)(blockIdx.x & 63) << 8);
        atomicAdd(&sp[2 * t],           ssx);
        atomicAdd(&sp[2 * t + 1],       ssy);
        atomicAdd(&sp[128 + 2 * t],     sqx);
        atomicAdd(&sp[128 + 2 * t + 1], sqy);
    }
}

// ---------- BN finalize: reduce spart slices, then scale/shift ----------
__global__ void k_bnfin(const float* __restrict__ spart, float* __restrict__ stats,
                        const float* __restrict__ gamma,
                        const float* __restrict__ beta, int N) {
    __shared__ float sred[256];
    int t = threadIdx.x;   // 256 threads
    float s = 0.f;
    for (int sl = 0; sl < 64; ++sl) s += spart[sl * 256 + t];
    sred[t] = s;
    __syncthreads();
    if (t < 128) {
        float invN = 1.0f / (float)N;
        float mean = sred[t] * invN;
        float var = sred[128 + t] * invN - mean * mean;
        var = fmaxf(var, 0.f);
        float inv = rsqrtf(var + 1e-5f);
        float sc = gamma[t] * inv;
        stats[256 + t] = sc;
        stats[384 + t] = beta[t] - mean * sc;
    }
}

// ---------- GEMM2 (MFMA): h2s[n][o] (bf16) = dis[n]*(relu(bn(agg1[n]))·W2[o])
__global__ __launch_bounds__(256) void k_gemm2(const float* __restrict__ agg1,
                                               const uint4* __restrict__ Whi,
                                               const uint4* __restrict__ Wlo,
                                               const float* __restrict__ stats,
                                               const float* __restrict__ dis,
                                               unsigned short* __restrict__ h2b, int N) {
    __shared__ uint4 Ahi[1024];   // [ (c*4+kt)*64 + lane ]
    __shared__ uint4 Alo[1024];
    int t = threadIdx.x;
    int n0 = blockIdx.x * 64;
    const float4* st = (const float4*)stats;
    // ---- phase 1: relu(bn(agg1)) -> hi/lo fragments in LDS ----
    for (int s = t; s < 1024; s += 256) {
        int lane = s & 63, kt = (s >> 6) & 3, c = s >> 8;
        int row = n0 + c * 16 + (lane & 15);
        int rr = min(row, N - 1);
        int k0 = kt * 32 + (lane >> 4) * 8;
        const float4* p = (const float4*)(agg1 + (size_t)rr * 128 + k0);
        float4 a0 = p[0], a1 = p[1];
        float4 c0 = st[64 + (k0 >> 2)], c1 = st[65 + (k0 >> 2)];
        float4 s0 = st[96 + (k0 >> 2)], s1 = st[97 + (k0 >> 2)];
        float v0 = fmaxf(a0.x * c0.x + s0.x, 0.f);
        float v1 = fmaxf(a0.y * c0.y + s0.y, 0.f);
        float v2 = fmaxf(a0.z * c0.z + s0.z, 0.f);
        float v3 = fmaxf(a0.w * c0.w + s0.w, 0.f);
        float v4 = fmaxf(a1.x * c1.x + s1.x, 0.f);
        float v5 = fmaxf(a1.y * c1.y + s1.y, 0.f);
        float v6 = fmaxf(a1.z * c1.z + s1.z, 0.f);
        float v7 = fmaxf(a1.w * c1.w + s1.w, 0.f);
        unsigned int h0, h1, h2, h3, l0, l1, l2, l3;
        split2(v0, v1, h0, l0);
        split2(v2, v3, h1, l1);
        split2(v4, v5, h2, l2);
        split2(v6, v7, h3, l3);
        Ahi[s] = make_uint4(h0, h1, h2, h3);
        Alo[s] = make_uint4(l0, l1, l2, l3);
    }
    __syncthreads();
    // ---- phase 2: MFMA (4 nt x 4 kt x 3) ----
    int w = t >> 6, lane = t & 63;
    bf16x8 ah[4], al[4];
#pragma unroll
    for (int kt = 0; kt < 4; ++kt) {
        ah[kt] = ((const bf16x8*)Ahi)[(w * 4 + kt) * 64 + lane];
        al[kt] = ((const bf16x8*)Alo)[(w * 4 + kt) * 64 + lane];
    }
    f32x4 acc[4];
#pragma unroll
    for (int nt = 0; nt < 4; ++nt) {
        acc[nt] = (f32x4)(0.f);
#pragma unroll
        for (int kt = 0; kt < 4; ++kt) {
            bf16x8 bh = ((const bf16x8*)Whi)[(nt * 4 + kt) * 64 + lane];
            bf16x8 bl = ((const bf16x8*)Wlo)[(nt * 4 + kt) * 64 + lane];
            acc[nt] = __builtin_amdgcn_mfma_f32_16x16x32_bf16(ah[kt], bh, acc[nt], 0, 0, 0);
            acc[nt] = __builtin_amdgcn_mfma_f32_16x16x32_bf16(ah[kt], bl, acc[nt], 0, 0, 0);
            acc[nt] = __builtin_amdgcn_mfma_f32_16x16x32_bf16(al[kt], bh, acc[nt], 0, 0, 0);
        }
    }
    // ---- epilogue: scale by dis, pack bf16, store (64 cols) ----
    int r0 = n0 + w * 16 + (lane >> 4) * 4;
    float dv[4];
#pragma unroll
    for (int r = 0; r < 4; ++r) {
        int row = r0 + r;
        dv[r] = (row < N) ? dis[row] : 0.f;
    }
#pragma unroll
    for (int nt = 0; nt < 4; ++nt) {
        int col = nt * 16 + (lane & 15);
#pragma unroll
        for (int r = 0; r < 4; ++r) {
            int row = r0 + r;
            if (row < N) h2b[(size_t)row * 64 + col] = f2bf(dv[r] * acc[nt][r]);
        }
    }
}

// ---------- layer-2 gather: pre-scaled bf16 rows, 16-way prefetch ----------
__global__ __launch_bounds__(256) void k_agg2(const unsigned short* __restrict__ h2b,
                                              const float* __restrict__ dis,
                                              const int* __restrict__ rowptr,
                                              const int* __restrict__ cnt,
                                              const int* __restrict__ elist,
                                              const float* __restrict__ b2,
                                              float* __restrict__ out, int N) {
    int lane = threadIdx.x & 63;
    int i = blockIdx.x * 4 + (threadIdx.x >> 6);
    if (i >= N) return;
    float acc = 0.f;
    int base = rowptr[i], c = cnt[i];
    int j = 0;
    for (; j + 16 <= c; j += 16) {
        int ss[16];
#pragma unroll
        for (int r = 0; r < 16; ++r) ss[r] = elist[base + j + r];
        unsigned short vv[16];
#pragma unroll
        for (int r = 0; r < 16; ++r) vv[r] = h2b[(size_t)ss[r] * 64 + lane];  // 128B/row
#pragma unroll
        for (int r = 0; r < 16; ++r) acc += bf2f(vv[r]);
    }
    if (j + 8 <= c) {
        int ss[8];
#pragma unroll
        for (int r = 0; r < 8; ++r) ss[r] = elist[base + j + r];
        unsigned short vv[8];
#pragma unroll
        for (int r = 0; r < 8; ++r) vv[r] = h2b[(size_t)ss[r] * 64 + lane];
#pragma unroll
        for (int r = 0; r < 8; ++r) acc += bf2f(vv[r]);
        j += 8;
    }
    for (; j < c; ++j) {
        int s = elist[base + j];
        acc += bf2f(h2b[(size_t)s * 64 + lane]);
    }
    float di = dis[i];
    float self = bf2f(h2b[(size_t)i * 64 + lane]);
    out[(size_t)i * 64 + lane] = di * (acc + self) + b2[lane];
}

extern "C" void kernel_launch(void* const* d_in, const int* in_sizes, int n_in,
                              void* d_out, int out_size, void* d_ws, size_t ws_size,
                              hipStream_t stream) {
    const float* x     = (const float*)d_in[0];
    const void*  ei    = d_in[1];            // int64 or int32, probed per-block
    const float* W1    = (const float*)d_in[2];
    // d_in[3] = b1: cancels exactly through BatchNorm -> skipped
    const float* gamma = (const float*)d_in[4];
    const float* beta  = (const float*)d_in[5];
    const float* W2    = (const float*)d_in[6];
    const float* b2    = (const float*)d_in[7];
    float* out = (float*)d_out;

    int N = in_sizes[0] / 128;
    int E = in_sizes[1] / 2;
    int NB = (N + BSZ - 1) >> SHIFT;         // 391 buckets for N=100000 (<= NBMAX)

    // ---- workspace layout (~85 MB; all regions 16B-aligned) ----
    size_t Na = ((size_t)N + 3) & ~(size_t)3;
    size_t Ea = ((size_t)E + 3) & ~(size_t)3;
    int*   cnt    = (int*)d_ws;                          // Na
    int*   rowptr = cnt + Na;                            // Na
    int*   gcnt   = rowptr + Na;                         // 1024
    int*   gbase  = gcnt + 1024;                         // 1028 (NB+1 used)
    int*   gcur   = gbase + 1028;                        // 1024
    float* stats  = (float*)(gcur + 1024);               // 512
    float* spart  = stats + 512;                         // 64*256 = 16K floats
    float* dis    = spart + 65536;                       // Na
    int*   elist  = (int*)(dis + Na);                    // Ea
    unsigned int* h1b = (unsigned int*)(elist + Ea);     // Na*64 uints (bf16x2)
    float* agg1   = (float*)(h1b + Na * 64);             // Na*128 f32
    unsigned int* ebuf = (unsigned int*)agg1;            // overlay: dead before k_agg1
    uint4* Whi1   = (uint4*)(agg1 + Na * 128);           // 2048 uint4 = 32 KB
    uint4* Wlo1   = Whi1 + 2048;                         // 32 KB
    uint4* Whi2   = Wlo1 + 2048;                         // 1024 uint4 = 16 KB
    uint4* Wlo2   = Whi2 + 1024;                         // 16 KB
    unsigned int* h2b = h1b;                             // overlay: h1 dead after agg1

    int gC    = (E + CHUNK - 1) / CHUNK;     // 391 chunks
    int gB    = gC > NB ? gC : NB;           // build grid
    if (gB < 12) gB = 12;
    int gG1   = (N + 63) / 64;               // MFMA gemms: 64 rows/block
    int gAgg1 = (N + 15) / 16;               // 16 nodes/block
    int gAgg2 = (N + 3) / 4;

    void* bargs[] = { (void*)&ei, (void*)&E, (void*)&N, (void*)&NB,
                      (void*)&gcnt, (void*)&gbase, (void*)&gcur, (void*)&ebuf,
                      (void*)&cnt, (void*)&dis, (void*)&rowptr, (void*)&elist,
                      (void*)&W1, (void*)&W2,
                      (void*)&Whi1, (void*)&Wlo1, (void*)&Whi2, (void*)&Wlo2,
                      (void*)&spart };
    hipLaunchCooperativeKernel((const void*)k_build, dim3(gB), dim3(256),
                               bargs, 0, stream);

    k_gemm1<<<gG1, 256, 0, stream>>>(x, Whi1, Wlo1, dis, (unsigned short*)h1b, N);
    k_agg1<<<gAgg1, 256, 0, stream>>>(h1b, dis, rowptr, cnt, elist, agg1, spart, N);
    k_bnfin<<<1, 256, 0, stream>>>(spart, stats, gamma, beta, N);
    k_gemm2<<<gG1, 256, 0, stream>>>(agg1, Whi2, Wlo2, stats, dis, (unsigned short*)h2b, N);
    k_agg2<<<gAgg2, 256, 0, stream>>>((const unsigned short*)h2b, dis, rowptr, cnt, elist, b2, out, N);
}

// Round 7
// 380.037 us; speedup vs baseline: 1.9009x; 1.9009x over previous
//
#include <hip/hip_runtime.h>

// GCNEncoder — round 17: REVERT R16's cooperative build (grid.sync cost ~90us
// each x4 = 380us spin-wait; counters: VALUBusy 0.5%, occupancy 18%).
// Back to R15's proven split chain (384.9us), plus two launch consolidations:
// - k_prep: weight fragment conversion + zeroing of gcnt/spart (replaces
//   2 hipMemsetAsync + k_prepw).
// - k_bnfin folded into k_gemm2 prologue (per-block redundant reduce of the
//   64KB L2-hot spart -> BN coeffs in LDS; removes the 1-block launch).
// Dispatches 12 -> 9. Hot kernels (agg1/agg2/gemm1 core) byte-identical.

#define SHIFT 8
#define BSZ   256          // nodes per bucket = 1<<SHIFT
#define CHUNK 4096         // edges per block in hist/scatter
#define EPT   (CHUNK/256)  // edges per thread = 16
#define NBMAX 1024         // supports N <= 262144

typedef short bf16x8 __attribute__((ext_vector_type(8)));
typedef float f32x4  __attribute__((ext_vector_type(4)));

__device__ __forceinline__ unsigned short f2bf(float f) {
    unsigned int u = __float_as_uint(f);
    unsigned int r = (u + 0x7FFFu + ((u >> 16) & 1u)) >> 16;   // RNE
    return (unsigned short)r;
}
__device__ __forceinline__ float bf2f(unsigned short h) {
    return __uint_as_float(((unsigned int)h) << 16);
}
// exact hi/lo split of a float pair, packed as bf16x2 (truncation split:
// x == bf2f(hi) + lo exactly; lo then truncated to bf16, residual ~2^-17|x|)
__device__ __forceinline__ void split2(float a, float b, unsigned int& hi, unsigned int& lo) {
    unsigned int ua = __float_as_uint(a), ub = __float_as_uint(b);
    unsigned int ha = ua & 0xFFFF0000u,  hb = ub & 0xFFFF0000u;
    hi = (ha >> 16) | hb;
    float la = a - __uint_as_float(ha);
    float lb = b - __uint_as_float(hb);
    lo = (__float_as_uint(la) >> 16) | (__float_as_uint(lb) & 0xFFFF0000u);
}
// dtype probe, computed per-block (reads 16 L2-hot ints): 1 => int64 input
__device__ __forceinline__ int detect64(const int* __restrict__ p) {
    int o = 0;
#pragma unroll
    for (int q = 0; q < 16; ++q) o |= p[2 * q + 1];
    return (o == 0) ? 1 : 0;
}

// ---------- prep: W1+W2 -> fragment bf16 hi/lo buffers + zero gcnt/spart ----
// slot = (nt*4 + kt)*64 + lane ; lane holds B[k][n] for n = nt*16+(lane&15),
// k = kt*32 + 8*(lane>>4) + j, j=0..7 packed low-to-high (same k-map as A).
__global__ __launch_bounds__(256) void k_prep(const float* __restrict__ W1,
                                              const float* __restrict__ W2,
                                              uint4* __restrict__ Whi1,
                                              uint4* __restrict__ Wlo1,
                                              uint4* __restrict__ Whi2,
                                              uint4* __restrict__ Wlo2,
                                              int* __restrict__ gcnt,
                                              float* __restrict__ spart) {
    int gid = blockIdx.x * 256 + threadIdx.x;   // 16 blocks = 4096 threads
    if (gid < 1024) gcnt[gid] = 0;
    for (int u = gid; u < 16384; u += 4096) spart[u] = 0.f;
    const float* W; uint4 *H, *L; int slot;
    if (gid < 2048)      { W = W1; H = Whi1; L = Wlo1; slot = gid; }
    else if (gid < 3072) { W = W2; H = Whi2; L = Wlo2; slot = gid - 2048; }
    else return;
    int lane = slot & 63, kt = (slot >> 6) & 3, nt = slot >> 8;
    int o = nt * 16 + (lane & 15);
    int k0 = kt * 32 + (lane >> 4) * 8;
    const float* p = W + (size_t)o * 128 + k0;
    unsigned int h[4], l[4];
#pragma unroll
    for (int pr = 0; pr < 4; ++pr) split2(p[2 * pr], p[2 * pr + 1], h[pr], l[pr]);
    H[slot] = make_uint4(h[0], h[1], h[2], h[3]);
    L[slot] = make_uint4(l[0], l[1], l[2], l[3]);
}

// ---------- pass 1: bucket histogram (LDS-staged) ----------
__global__ __launch_bounds__(256) void k_hist(const void* __restrict__ eiv,
                                              int* __restrict__ gcnt,
                                              int E, int N, int NB) {
    __shared__ int h[NBMAX];
    int t = threadIdx.x;
    for (int u = t; u < NB; u += 256) h[u] = 0;
    __syncthreads();
    int base = blockIdx.x * CHUNK;
    int f = detect64((const int*)eiv);
    const long long* e64 = (const long long*)eiv;
    const int*       e32 = (const int*)eiv;
#pragma unroll
    for (int r = 0; r < EPT; ++r) {
        int e = base + r * 256 + t;
        if (e < E) {
            int s, d;
            if (f) { s = (int)e64[e]; d = (int)e64[E + e]; }
            else   { s = e32[e];      d = e32[E + e]; }
            if ((unsigned)s < (unsigned)N && (unsigned)d < (unsigned)N)
                atomicAdd(&h[d >> SHIFT], 1);
        }
    }
    __syncthreads();
    for (int u = t; u < NB; u += 256) {
        int c = h[u];
        if (c) atomicAdd(&gcnt[u], c);
    }
}

// ---------- pass 2: exclusive prefix over bucket totals ----------
__global__ void k_scan(const int* __restrict__ gcnt, int* __restrict__ gbase,
                       int* __restrict__ gcur, int NB) {
    __shared__ int sh[1024];
    int t = threadIdx.x;
    int v = (t < NB) ? gcnt[t] : 0;
    sh[t] = v;
    __syncthreads();
    for (int off = 1; off < 1024; off <<= 1) {
        int x = sh[t];
        int y = (t >= off) ? sh[t - off] : 0;
        __syncthreads();
        sh[t] = x + y;
        __syncthreads();
    }
    if (t < NB) {
        int ex = sh[t] - v;
        gbase[t] = ex;
        gcur[t]  = ex;
    }
    if (t == 0) gbase[NB] = sh[1023];
}

// ---------- pass 3: scatter edges into bucket regions, clustered ----------
__global__ __launch_bounds__(256) void k_scatter(const void* __restrict__ eiv,
                                                 int* __restrict__ gcur,
                                                 unsigned int* __restrict__ ebuf,
                                                 int E, int N, int NB) {
    __shared__ int lcnt[NBMAX];
    __shared__ int lbase[NBMAX];
    int t = threadIdx.x;
    for (int u = t; u < NB; u += 256) lcnt[u] = 0;
    __syncthreads();
    int base = blockIdx.x * CHUNK;
    int f = detect64((const int*)eiv);
    const long long* e64 = (const long long*)eiv;
    const int*       e32 = (const int*)eiv;
    unsigned int ent[EPT];
    int bk[EPT];
    int off[EPT];
#pragma unroll
    for (int r = 0; r < EPT; ++r) {
        int e = base + r * 256 + t;
        bk[r] = -1;
        if (e < E) {
            int s, d;
            if (f) { s = (int)e64[e]; d = (int)e64[E + e]; }
            else   { s = e32[e];      d = e32[E + e]; }
            if ((unsigned)s < (unsigned)N && (unsigned)d < (unsigned)N) {
                int b = d >> SHIFT;
                bk[r]  = b;
                off[r] = atomicAdd(&lcnt[b], 1);
                ent[r] = ((unsigned int)(d & (BSZ - 1)) << 24) | (unsigned int)s;
            }
        }
    }
    __syncthreads();
    for (int u = t; u < NB; u += 256) {
        int c = lcnt[u];
        lbase[u] = c ? atomicAdd(&gcur[u], c) : 0;
    }
    __syncthreads();
#pragma unroll
    for (int r = 0; r < EPT; ++r)
        if (bk[r] >= 0) ebuf[(size_t)lbase[bk[r]] + off[r]] = ent[r];
}

// ---------- pass 4: per-bucket CSR finalize (counts, dis, rowptr, elist) ----
__global__ __launch_bounds__(256) void k_fine(const unsigned int* __restrict__ ebuf,
                                              const int* __restrict__ gbase,
                                              int* __restrict__ cnt,
                                              float* __restrict__ dis,
                                              int* __restrict__ rowptr,
                                              int* __restrict__ elist, int N) {
    __shared__ int lc[BSZ];
    __shared__ int ls[BSZ];
    int t = threadIdx.x;
    int b = blockIdx.x;
    int start = gbase[b], end = gbase[b + 1];
    int m = end - start;
    lc[t] = 0;
    __syncthreads();
    for (int j = t; j < m; j += 256)
        atomicAdd(&lc[ebuf[start + j] >> 24], 1);
    __syncthreads();
    int v = lc[t];
    ls[t] = v;
    __syncthreads();
    for (int off = 1; off < BSZ; off <<= 1) {
        int x = ls[t];
        int y = (t >= off) ? ls[t - off] : 0;
        __syncthreads();
        ls[t] = x + y;
        __syncthreads();
    }
    int ex = ls[t] - v;
    int i = (b << SHIFT) + t;
    if (i < N) {
        cnt[i]    = v;
        dis[i]    = rsqrtf((float)v + 1.0f);
        rowptr[i] = start + ex;
    }
    lc[t] = ex;        // per-node cursor (bucket-relative)
    __syncthreads();
    for (int j = t; j < m; j += 256) {
        unsigned int e = ebuf[start + j];
        int p = atomicAdd(&lc[e >> 24], 1);
        elist[start + p] = (int)(e & 0xFFFFFFu);
    }
}

// ---------- GEMM1 (MFMA): h1s[n][o] (bf16) = dis[n] * (x[n]·W1[o]) ----------
__global__ __launch_bounds__(256) void k_gemm1(const float* __restrict__ x,
                                               const uint4* __restrict__ Whi,
                                               const uint4* __restrict__ Wlo,
                                               const float* __restrict__ dis,
                                               unsigned short* __restrict__ h1b, int N) {
    __shared__ uint4 Ahi[1024];   // [ (c*4+kt)*64 + lane ]
    __shared__ uint4 Alo[1024];
    int t = threadIdx.x;
    int n0 = blockIdx.x * 64;
    // ---- phase 1: x -> hi/lo fragments in LDS ----
    for (int s = t; s < 1024; s += 256) {
        int lane = s & 63, kt = (s >> 6) & 3, c = s >> 8;
        int row = n0 + c * 16 + (lane & 15);
        int rr = min(row, N - 1);
        int k0 = kt * 32 + (lane >> 4) * 8;
        const float4* p = (const float4*)(x + (size_t)rr * 128 + k0);
        float4 u0 = p[0], u1 = p[1];
        unsigned int h0, h1, h2, h3, l0, l1, l2, l3;
        split2(u0.x, u0.y, h0, l0);
        split2(u0.z, u0.w, h1, l1);
        split2(u1.x, u1.y, h2, l2);
        split2(u1.z, u1.w, h3, l3);
        Ahi[s] = make_uint4(h0, h1, h2, h3);
        Alo[s] = make_uint4(l0, l1, l2, l3);
    }
    __syncthreads();
    // ---- phase 2: MFMA ----
    int w = t >> 6, lane = t & 63;
    bf16x8 ah[4], al[4];
#pragma unroll
    for (int kt = 0; kt < 4; ++kt) {
        ah[kt] = ((const bf16x8*)Ahi)[(w * 4 + kt) * 64 + lane];
        al[kt] = ((const bf16x8*)Alo)[(w * 4 + kt) * 64 + lane];
    }
    f32x4 acc[8];
#pragma unroll
    for (int nt = 0; nt < 8; ++nt) {
        acc[nt] = (f32x4)(0.f);
#pragma unroll
        for (int kt = 0; kt < 4; ++kt) {
            bf16x8 bh = ((const bf16x8*)Whi)[(nt * 4 + kt) * 64 + lane];
            bf16x8 bl = ((const bf16x8*)Wlo)[(nt * 4 + kt) * 64 + lane];
            acc[nt] = __builtin_amdgcn_mfma_f32_16x16x32_bf16(ah[kt], bh, acc[nt], 0, 0, 0);
            acc[nt] = __builtin_amdgcn_mfma_f32_16x16x32_bf16(ah[kt], bl, acc[nt], 0, 0, 0);
            acc[nt] = __builtin_amdgcn_mfma_f32_16x16x32_bf16(al[kt], bh, acc[nt], 0, 0, 0);
        }
    }
    // ---- epilogue: scale by dis, pack bf16, store ----
    int r0 = n0 + w * 16 + (lane >> 4) * 4;
    float dv[4];
#pragma unroll
    for (int r = 0; r < 4; ++r) {
        int row = r0 + r;
        dv[r] = (row < N) ? dis[row] : 0.f;
    }
#pragma unroll
    for (int nt = 0; nt < 8; ++nt) {
        int col = nt * 16 + (lane & 15);
#pragma unroll
        for (int r = 0; r < 4; ++r) {
            int row = r0 + r;
            if (row < N) h1b[(size_t)row * 128 + col] = f2bf(dv[r] * acc[nt][r]);
        }
    }
}

// ---------- layer-1 gather + fused BN-stats, 16 nodes/block ----------
// agg1[i] = dis_i * ( sum_edges h1s[s] + h1s[i] ); each wave processes 4
// sequential nodes, BN partials held in registers across nodes; one LDS
// reduce + 256 atomics per block into spart[bid&63][256].
__global__ __launch_bounds__(256) void k_agg1(const unsigned int* __restrict__ h1b,
                                              const float* __restrict__ dis,
                                              const int* __restrict__ rowptr,
                                              const int* __restrict__ cnt,
                                              const int* __restrict__ elist,
                                              float* __restrict__ agg1,
                                              float* __restrict__ spart, int N) {
    int t = threadIdx.x;
    int lane = t & 63;
    int i0 = blockIdx.x * 16 + (t >> 6) * 4;
    float sx = 0.f, sy = 0.f, qx = 0.f, qy = 0.f;
#pragma unroll
    for (int k = 0; k < 4; ++k) {
        int i = i0 + k;
        bool act = (i < N);
        float accx = 0.f, accy = 0.f;
        int base = 0, c = 0;
        if (act) { base = rowptr[i]; c = cnt[i]; }
        int j = 0;
        for (; j + 16 <= c; j += 16) {
            int ss[16];
#pragma unroll
            for (int r = 0; r < 16; ++r) ss[r] = elist[base + j + r];
            unsigned int vv[16];
#pragma unroll
            for (int r = 0; r < 16; ++r) vv[r] = h1b[(size_t)ss[r] * 64 + lane];  // 256B/row
#pragma unroll
            for (int r = 0; r < 16; ++r) {
                accx += bf2f((unsigned short)(vv[r] & 0xFFFF));
                accy += bf2f((unsigned short)(vv[r] >> 16));
            }
        }
        if (j + 8 <= c) {
            int ss[8];
#pragma unroll
            for (int r = 0; r < 8; ++r) ss[r] = elist[base + j + r];
            unsigned int vv[8];
#pragma unroll
            for (int r = 0; r < 8; ++r) vv[r] = h1b[(size_t)ss[r] * 64 + lane];
#pragma unroll
            for (int r = 0; r < 8; ++r) {
                accx += bf2f((unsigned short)(vv[r] & 0xFFFF));
                accy += bf2f((unsigned short)(vv[r] >> 16));
            }
            j += 8;
        }
        for (; j < c; ++j) {
            int s = elist[base + j];
            unsigned int v = h1b[(size_t)s * 64 + lane];
            accx += bf2f((unsigned short)(v & 0xFFFF));
            accy += bf2f((unsigned short)(v >> 16));
        }
        if (act) {
            float di = dis[i];
            unsigned int sv = h1b[(size_t)i * 64 + lane];
            float rx = di * (accx + bf2f((unsigned short)(sv & 0xFFFF)));
            float ry = di * (accy + bf2f((unsigned short)(sv >> 16)));
            ((float2*)agg1)[(size_t)i * 64 + lane] = make_float2(rx, ry);
            sx += rx; sy += ry; qx += rx * rx; qy += ry * ry;
        }
    }
    // ---- fused BN partial stats: features 2*lane, 2*lane+1 ----
    __shared__ float4 red[256];
    red[t] = make_float4(sx, sy, qx, qy);
    __syncthreads();
    if (t < 64) {
        float4 a = red[t], b = red[t + 64], cc = red[t + 128], d = red[t + 192];
        float ssx = a.x + b.x + cc.x + d.x;
        float ssy = a.y + b.y + cc.y + d.y;
        float sqx = a.z + b.z + cc.z + d.z;
        float sqy = a.w + b.w + cc.w + d.w;
        float* sp = spart + ((size_t)(blockIdx.x & 63) << 8);
        atomicAdd(&sp[2 * t],           ssx);
        atomicAdd(&sp[2 * t + 1],       ssy);
        atomicAdd(&sp[128 + 2 * t],     sqx);
        atomicAdd(&sp[128 + 2 * t + 1], sqy);
    }
}

// ---------- GEMM2 (MFMA) + fused BN finalize ----------
// h2s[n][o] (bf16) = dis[n]*(relu(bn(agg1[n]))·W2[o]); each block redundantly
// reduces the 64KB L2-hot spart -> BN scale/shift in LDS (removes k_bnfin).
__global__ __launch_bounds__(256) void k_gemm2(const float* __restrict__ agg1,
                                               const uint4* __restrict__ Whi,
                                               const uint4* __restrict__ Wlo,
                                               const float* __restrict__ spart,
                                               const float* __restrict__ gamma,
                                               const float* __restrict__ beta,
                                               const float* __restrict__ dis,
                                               unsigned short* __restrict__ h2b, int N) {
    __shared__ uint4 Ahi[1024];   // [ (c*4+kt)*64 + lane ]
    __shared__ uint4 Alo[1024];
    __shared__ float sred[256];
    __shared__ float bnsc[128], bnsh[128];
    int t = threadIdx.x;
    int n0 = blockIdx.x * 64;
    // ---- phase 0: BN finalize (redundant per block; spart is L2-hot) ----
    {
        float s = 0.f;
        for (int sl = 0; sl < 64; ++sl) s += spart[sl * 256 + t];
        sred[t] = s;
        __syncthreads();
        if (t < 128) {
            float invN = 1.0f / (float)N;
            float mean = sred[t] * invN;
            float var = sred[128 + t] * invN - mean * mean;
            var = fmaxf(var, 0.f);
            float inv = rsqrtf(var + 1e-5f);
            float sc = gamma[t] * inv;
            bnsc[t] = sc;
            bnsh[t] = beta[t] - mean * sc;
        }
        __syncthreads();
    }
    // ---- phase 1: relu(bn(agg1)) -> hi/lo fragments in LDS ----
    for (int s = t; s < 1024; s += 256) {
        int lane = s & 63, kt = (s >> 6) & 3, c = s >> 8;
        int row = n0 + c * 16 + (lane & 15);
        int rr = min(row, N - 1);
        int k0 = kt * 32 + (lane >> 4) * 8;
        const float4* p = (const float4*)(agg1 + (size_t)rr * 128 + k0);
        float4 a0 = p[0], a1 = p[1];
        float v0 = fmaxf(a0.x * bnsc[k0 + 0] + bnsh[k0 + 0], 0.f);
        float v1 = fmaxf(a0.y * bnsc[k0 + 1] + bnsh[k0 + 1], 0.f);
        float v2 = fmaxf(a0.z * bnsc[k0 + 2] + bnsh[k0 + 2], 0.f);
        float v3 = fmaxf(a0.w * bnsc[k0 + 3] + bnsh[k0 + 3], 0.f);
        float v4 = fmaxf(a1.x * bnsc[k0 + 4] + bnsh[k0 + 4], 0.f);
        float v5 = fmaxf(a1.y * bnsc[k0 + 5] + bnsh[k0 + 5], 0.f);
        float v6 = fmaxf(a1.z * bnsc[k0 + 6] + bnsh[k0 + 6], 0.f);
        float v7 = fmaxf(a1.w * bnsc[k0 + 7] + bnsh[k0 + 7], 0.f);
        unsigned int h0, h1, h2, h3, l0, l1, l2, l3;
        split2(v0, v1, h0, l0);
        split2(v2, v3, h1, l1);
        split2(v4, v5, h2, l2);
        split2(v6, v7, h3, l3);
        Ahi[s] = make_uint4(h0, h1, h2, h3);
        Alo[s] = make_uint4(l0, l1, l2, l3);
    }
    __syncthreads();
    // ---- phase 2: MFMA (4 nt x 4 kt x 3) ----
    int w = t >> 6, lane = t & 63;
    bf16x8 ah[4], al[4];
#pragma unroll
    for (int kt = 0; kt < 4; ++kt) {
        ah[kt] = ((const bf16x8*)Ahi)[(w * 4 + kt) * 64 + lane];
        al[kt] = ((const bf16x8*)Alo)[(w * 4 + kt) * 64 + lane];
    }
    f32x4 acc[4];
#pragma unroll
    for (int nt = 0; nt < 4; ++nt) {
        acc[nt] = (f32x4)(0.f);
#pragma unroll
        for (int kt = 0; kt < 4; ++kt) {
            bf16x8 bh = ((const bf16x8*)Whi)[(nt * 4 + kt) * 64 + lane];
            bf16x8 bl = ((const bf16x8*)Wlo)[(nt * 4 + kt) * 64 + lane];
            acc[nt] = __builtin_amdgcn_mfma_f32_16x16x32_bf16(ah[kt], bh, acc[nt], 0, 0, 0);
            acc[nt] = __builtin_amdgcn_mfma_f32_16x16x32_bf16(ah[kt], bl, acc[nt], 0, 0, 0);
            acc[nt] = __builtin_amdgcn_mfma_f32_16x16x32_bf16(al[kt], bh, acc[nt], 0, 0, 0);
        }
    }
    // ---- epilogue: scale by dis, pack bf16, store (64 cols) ----
    int r0 = n0 + w * 16 + (lane >> 4) * 4;
    float dv[4];
#pragma unroll
    for (int r = 0; r < 4; ++r) {
        int row = r0 + r;
        dv[r] = (row < N) ? dis[row] : 0.f;
    }
#pragma unroll
    for (int nt = 0; nt < 4; ++nt) {
        int col = nt * 16 + (lane & 15);
#pragma unroll
        for (int r = 0; r < 4; ++r) {
            int row = r0 + r;
            if (row < N) h2b[(size_t)row * 64 + col] = f2bf(dv[r] * acc[nt][r]);
        }
    }
}

// ---------- layer-2 gather: pre-scaled bf16 rows, 16-way prefetch ----------
// out[i] = dis_i * ( sum_edges h2s[s] + h2s[i] ) + b2
__global__ __launch_bounds__(256) void k_agg2(const unsigned short* __restrict__ h2b,
                                              const float* __restrict__ dis,
                                              const int* __restrict__ rowptr,
                                              const int* __restrict__ cnt,
                                              const int* __restrict__ elist,
                                              const float* __restrict__ b2,
                                              float* __restrict__ out, int N) {
    int lane = threadIdx.x & 63;
    int i = blockIdx.x * 4 + (threadIdx.x >> 6);
    if (i >= N) return;
    float acc = 0.f;
    int base = rowptr[i], c = cnt[i];
    int j = 0;
    for (; j + 16 <= c; j += 16) {
        int ss[16];
#pragma unroll
        for (int r = 0; r < 16; ++r) ss[r] = elist[base + j + r];
        unsigned short vv[16];
#pragma unroll
        for (int r = 0; r < 16; ++r) vv[r] = h2b[(size_t)ss[r] * 64 + lane];  // 128B/row
#pragma unroll
        for (int r = 0; r < 16; ++r) acc += bf2f(vv[r]);
    }
    if (j + 8 <= c) {
        int ss[8];
#pragma unroll
        for (int r = 0; r < 8; ++r) ss[r] = elist[base + j + r];
        unsigned short vv[8];
#pragma unroll
        for (int r = 0; r < 8; ++r) vv[r] = h2b[(size_t)ss[r] * 64 + lane];
#pragma unroll
        for (int r = 0; r < 8; ++r) acc += bf2f(vv[r]);
        j += 8;
    }
    for (; j < c; ++j) {
        int s = elist[base + j];
        acc += bf2f(h2b[(size_t)s * 64 + lane]);
    }
    float di = dis[i];
    float self = bf2f(h2b[(size_t)i * 64 + lane]);
    out[(size_t)i * 64 + lane] = di * (acc + self) + b2[lane];
}

extern "C" void kernel_launch(void* const* d_in, const int* in_sizes, int n_in,
                              void* d_out, int out_size, void* d_ws, size_t ws_size,
                              hipStream_t stream) {
    const float* x     = (const float*)d_in[0];
    const void*  ei    = d_in[1];            // int64 or int32, probed per-block
    const float* W1    = (const float*)d_in[2];
    // d_in[3] = b1: cancels exactly through BatchNorm -> skipped
    const float* gamma = (const float*)d_in[4];
    const float* beta  = (const float*)d_in[5];
    const float* W2    = (const float*)d_in[6];
    const float* b2    = (const float*)d_in[7];
    float* out = (float*)d_out;

    int N = in_sizes[0] / 128;
    int E = in_sizes[1] / 2;
    int NB = (N + BSZ - 1) >> SHIFT;         // 391 buckets for N=100000 (<= NBMAX)

    // ---- workspace layout (~85 MB; all regions 16B-aligned) ----
    size_t Na = ((size_t)N + 3) & ~(size_t)3;
    size_t Ea = ((size_t)E + 3) & ~(size_t)3;
    int*   cnt    = (int*)d_ws;                          // Na
    int*   rowptr = cnt + Na;                            // Na
    int*   gcnt   = rowptr + Na;                         // 1024
    int*   gbase  = gcnt + 1024;                         // 1028 (NB+1 used)
    int*   gcur   = gbase + 1028;                        // 1024
    float* stats  = (float*)(gcur + 1024);               // 512 (unused, kept for layout)
    float* spart  = stats + 512;                         // 64*256 = 16K floats
    float* dis    = spart + 65536;                       // Na
    int*   elist  = (int*)(dis + Na);                    // Ea
    unsigned int* h1b = (unsigned int*)(elist + Ea);     // Na*64 uints (bf16x2)
    float* agg1   = (float*)(h1b + Na * 64);             // Na*128 f32
    unsigned int* ebuf = (unsigned int*)agg1;            // overlay: dead before k_agg1
    uint4* Whi1   = (uint4*)(agg1 + Na * 128);           // 2048 uint4 = 32 KB
    uint4* Wlo1   = Whi1 + 2048;                         // 32 KB
    uint4* Whi2   = Wlo1 + 2048;                         // 1024 uint4 = 16 KB
    uint4* Wlo2   = Whi2 + 1024;                         // 16 KB
    unsigned int* h2b = h1b;                             // overlay: h1 dead after agg1

    int gC    = (E + CHUNK - 1) / CHUNK;     // 391 chunks
    int gG1   = (N + 63) / 64;               // MFMA gemms: 64 rows/block
    int gAgg1 = (N + 15) / 16;               // 16 nodes/block
    int gAgg2 = (N + 3) / 4;

    k_prep<<<16, 256, 0, stream>>>(W1, W2, Whi1, Wlo1, Whi2, Wlo2, gcnt, spart);
    k_hist<<<gC, 256, 0, stream>>>(ei, gcnt, E, N, NB);
    k_scan<<<1, 1024, 0, stream>>>(gcnt, gbase, gcur, NB);
    k_scatter<<<gC, 256, 0, stream>>>(ei, gcur, ebuf, E, N, NB);
    k_fine<<<NB, 256, 0, stream>>>(ebuf, gbase, cnt, dis, rowptr, elist, N);
    k_gemm1<<<gG1, 256, 0, stream>>>(x, Whi1, Wlo1, dis, (unsigned short*)h1b, N);
    k_agg1<<<gAgg1, 256, 0, stream>>>(h1b, dis, rowptr, cnt, elist, agg1, spart, N);
    k_gemm2<<<gG1, 256, 0, stream>>>(agg1, Whi2, Wlo2, spart, gamma, beta, dis, (unsigned short*)h2b, N);
    k_agg2<<<gAgg2, 256, 0, stream>>>((const unsigned short*)h2b, dis, rowptr, cnt, elist, b2, out, N);
}